// Round 5
// baseline (237.344 us; speedup 1.0000x reference)
//
#include <hip/hip_runtime.h>
#include <hip/hip_bf16.h>

#define B_ 16
#define C_ 256
#define L_ 2048
#define MT 32   // m-tile per iteration

typedef __attribute__((ext_vector_type(8))) short bf16x8;
typedef __attribute__((ext_vector_type(4))) float f32x4;

#define CEXP 0.09016844005556021f   // (1/16) * log2(e), folded into Q conversion

// round-to-nearest-even float -> bf16
__device__ __forceinline__ short f2bf_rne(float f) {
    union { float f; unsigned u; } x; x.f = f;
    unsigned r = x.u + 0x7fffu + ((x.u >> 16) & 1u);
    return (short)(r >> 16);
}

// direct global->LDS DMA, 16 bytes per lane; LDS dest = wave-uniform base + lane*16
__device__ __forceinline__ void gld_lds16(const void* g, void* l) {
    __builtin_amdgcn_global_load_lds(
        (const __attribute__((address_space(1))) void*)g,
        (__attribute__((address_space(3))) void*)l, 16, 0, 0);
}

// barrier that waits LDS ops only (lgkmcnt(0)), leaving DMA/global loads (vmcnt) in flight.
// 0xC07F = vmcnt 63, expcnt 7, lgkmcnt 0.
__device__ __forceinline__ void barrier_lds_only() {
    asm volatile("" ::: "memory");
    __builtin_amdgcn_s_waitcnt(0xC07F);
    __builtin_amdgcn_s_barrier();
    asm volatile("" ::: "memory");
}

// ---------------- prepass: K transpose+cvt (blocks 0..511), V*mask cvt (512..4607) ----------
__global__ __launch_bounds__(256) void prepass_kernel(
        const float* __restrict__ Kin, const float* __restrict__ Vin,
        const float* __restrict__ mask,
        short* __restrict__ Kt, short* __restrict__ Vb) {
    const int bid = blockIdx.x;
    const int t = threadIdx.x;
    if (bid < 512) {
        __shared__ unsigned short tile[64 * 256];   // 32 KB, phys chunk = (c>>3) ^ (l&31)
        const int b  = bid >> 5;
        const int l0 = (bid & 31) * 64;
        #pragma unroll
        for (int iter = 0; iter < 16; ++iter) {
            int idx = iter * 256 + t;              // 0..4095
            int ci = idx >> 4;                     // 0..255
            int lc = (idx & 15) * 4;               // l-chunk of 4
            float4 v = *(const float4*)(Kin + ((size_t)(b * C_ + ci)) * L_ + l0 + lc);
            float vv[4] = {v.x, v.y, v.z, v.w};
            #pragma unroll
            for (int j = 0; j < 4; ++j) {
                int l = lc + j;
                tile[l * 256 + (((ci >> 3) ^ (l & 31)) << 3) + (ci & 7)] =
                    (unsigned short)f2bf_rne(vv[j]);
            }
        }
        __syncthreads();
        #pragma unroll
        for (int iter = 0; iter < 8; ++iter) {
            int li = iter * 8 + (t >> 5);          // 0..63
            int ck = t & 31;                       // logical 16-B chunk
            uint4 val = *(const uint4*)(tile + li * 256 + ((ck ^ (li & 31)) << 3));
            *(uint4*)(Kt + ((size_t)(b * L_ + l0 + li)) * C_ + ck * 8) = val;
        }
    } else {
        // 4096 blocks x 256 threads x 8 elems = B_*C_*L_
        size_t e = ((size_t)(bid - 512) * 256 + t) * 8;
        int b = (int)(e >> 19);
        int m = (int)(e & (L_ - 1));
        const float4 v0 = *(const float4*)(Vin + e);
        const float4 v1 = *(const float4*)(Vin + e + 4);
        const float* mp = mask + ((size_t)b << 11) + m;
        const float4 m0 = *(const float4*)mp;
        const float4 m1 = *(const float4*)(mp + 4);
        uint4 o;
        o.x = (unsigned)(unsigned short)f2bf_rne(v0.x * m0.x)
            | ((unsigned)(unsigned short)f2bf_rne(v0.y * m0.y) << 16);
        o.y = (unsigned)(unsigned short)f2bf_rne(v0.z * m0.z)
            | ((unsigned)(unsigned short)f2bf_rne(v0.w * m0.w) << 16);
        o.z = (unsigned)(unsigned short)f2bf_rne(v1.x * m1.x)
            | ((unsigned)(unsigned short)f2bf_rne(v1.y * m1.y) << 16);
        o.w = (unsigned)(unsigned short)f2bf_rne(v1.z * m1.z)
            | ((unsigned)(unsigned short)f2bf_rne(v1.w * m1.w) << 16);
        *(uint4*)(Vb + e) = o;
    }
}

// ---- stage one 32-row K tile via DMA; XOR swizzle on the GLOBAL side ----
// K LDS: [m 0..31][slot p 0..31 of 16B]; phys slot p holds global chunk kc = p ^ m.
__device__ __forceinline__ void stage_K(const short* __restrict__ Ksrc,
                                        short* Ks, int m0, int t) {
    #pragma unroll
    for (int rr = 0; rr < 4; ++rr) {
        int G = rr * 256 + t;                  // 0..1023
        int m = G >> 5, p = G & 31;
        gld_lds16(Ksrc + ((size_t)(m0 + m) << 8) + ((p ^ m) << 3), Ks + G * 8);
    }
}

// V B-fragments direct global->register (B[k=8q+j][col=c] = Vb[c][m0+8q+j], 16B contiguous)
__device__ __forceinline__ void load_V(bf16x8 (&vf)[4], const short* __restrict__ Vw, int m0) {
    #pragma unroll
    for (int ct = 0; ct < 4; ++ct)
        vf[ct] = *(const bf16x8*)(Vw + (size_t)(ct * 16) * L_ + m0);
}

// one m-tile iteration.  P row permutation: logical l=32g+16lt+4q+r stored at rho=32g+16lt+4r+q
// (q-step = 20 words -> write banks {0,20,8,28}+n/2, ~conflict-free; reads: 64 distinct chunks).
#define ATTN_ITER(KS_CUR, KS_NXT, VF_CUR, VF_NXT, M0, GUARD)                               \
  {                                                                                        \
    __syncthreads();  /* K[cur],V[cur] landed; prev O-phase done with P */                 \
    if (!(GUARD) || ((M0) + MT < L_)) {                                                    \
      stage_K(Ksrc, KS_NXT, (M0) + MT, t);                                                 \
      load_V(VF_NXT, Vw, (M0) + MT);                                                       \
    }                                                                                      \
    float wv = mrow[(M0) + 16 * mt + n] + 1e-9f;                                           \
    f32x4 S0 = fzero, S1 = fzero;                                                          \
    const short* Krow = KS_CUR + (16 * mt + n) * 256;                                      \
    _Pragma("unroll")                                                                      \
    for (int ks = 0; ks < 8; ++ks) {                                                       \
      bf16x8 bf = *(const bf16x8*)(Krow + (((4 * ks + q) ^ (16 * mt + n)) << 3));          \
      S0 = __builtin_amdgcn_mfma_f32_16x16x32_bf16(qf[0][ks], bf, S0, 0, 0, 0);            \
      S1 = __builtin_amdgcn_mfma_f32_16x16x32_bf16(qf[1][ks], bf, S1, 0, 0, 0);            \
    }                                                                                      \
    _Pragma("unroll")                                                                      \
    for (int r = 0; r < 4; ++r) {                                                          \
      float p0 = wv * exp2f(S0[r]);                                                        \
      dn[0][r] += p0;                                                                      \
      Pw0[(4 * r) * 40] = f2bf_rne(p0);                                                    \
      float p1 = wv * exp2f(S1[r]);                                                        \
      dn[1][r] += p1;                                                                      \
      Pw0[(16 + 4 * r) * 40] = f2bf_rne(p1);                                               \
    }                                                                                      \
    barrier_lds_only();  /* P visible; K-DMA + V loads stay in flight */                   \
    bf16x8 af[4];                                                                          \
    _Pragma("unroll")                                                                      \
    for (int lt = 0; lt < 4; ++lt)                                                         \
      af[lt] = *(const bf16x8*)(Pl + (16 * lt + 4 * (n & 3) + (n >> 2)) * 40 + 8 * q);     \
    _Pragma("unroll")                                                                      \
    for (int ct = 0; ct < 4; ++ct)                                                         \
      _Pragma("unroll")                                                                    \
      for (int lt = 0; lt < 4; ++lt)                                                       \
        Oacc[lt][ct] =                                                                     \
            __builtin_amdgcn_mfma_f32_16x16x32_bf16(af[lt], VF_CUR[ct], Oacc[lt][ct], 0, 0, 0); \
  }

// ---------------- main fused attention ----------------
// 512 blocks (b = bid&15, l0 = (bid>>4)*64), 4 waves.
// S-phase: wave (g=w&1, mt=w>>1): rows 32g..32g+31 x cols m=16mt+n.  Q A-frags from global.
// O-phase: wave w: cols c in [64w,64w+64) x 64 l; V B-frags direct from global (reg prefetch).
__global__ __launch_bounds__(256, 2) void attn_main(
        const float* __restrict__ Qin,  // [B][C][L] fp32 (original)
        const short* __restrict__ Kt,   // [B][L][C] bf16
        const short* __restrict__ Vb,   // [B][C][L] bf16, mask-scaled
        const float* __restrict__ mask, // [B][L]
        float* __restrict__ out) {      // [B][C][L]
    __shared__ __align__(16) char smem[38400];
    short* KsB0 = (short*)smem;                 // 16 KB
    short* KsB1 = (short*)(smem + 16384);       // 16 KB
    short* Pl   = (short*)(smem + 32768);       // [64 rho][40 shorts] = 5120 B
    float* Dsh  = (float*)(smem + 37888);       // [2][64] partial denoms, 512 B

    const int t = threadIdx.x;
    const int w = t >> 6, lane = t & 63, q = lane >> 4, n = lane & 15;
    const int g = w & 1, mt = w >> 1;

    const int b  = blockIdx.x & 15;
    const int l0 = (blockIdx.x >> 4) * 64;

    const short* Ksrc = Kt + (size_t)b * (L_ * C_);
    const short* Vsrc = Vb + (size_t)b * (C_ * L_);
    const float* mrow = mask + (size_t)b * L_;
    const short* Vw   = Vsrc + (size_t)(64 * w + n) * L_ + 8 * q;
    short* Pw0 = Pl + (32 * g + q) * 40 + 16 * mt + n;   // write base (lt/r offsets in macro)

    // ---- Q A-frags straight from global fp32 (once; blocks partition l so Q read exactly once)
    bf16x8 qf[2][8];
    {
        const float* Qb = Qin + (size_t)b * (C_ * L_) + (l0 + 32 * g + n);
        #pragma unroll
        for (int lt = 0; lt < 2; ++lt)
            #pragma unroll
            for (int ks = 0; ks < 8; ++ks) {
                bf16x8 v;
                #pragma unroll
                for (int j = 0; j < 8; ++j) {
                    float f = Qb[(size_t)(32 * ks + 8 * q + j) * L_ + 16 * lt];
                    v[j] = f2bf_rne(f * CEXP);
                }
                qf[lt][ks] = v;
            }
    }

    const f32x4 fzero = {0.f, 0.f, 0.f, 0.f};
    f32x4 Oacc[4][4];
    #pragma unroll
    for (int i = 0; i < 4; ++i)
        #pragma unroll
        for (int j = 0; j < 4; ++j) Oacc[i][j] = fzero;
    float dn[2][4] = {{0.f,0.f,0.f,0.f},{0.f,0.f,0.f,0.f}};

    // prologue: tile 0
    stage_K(Ksrc, KsB0, 0, t);
    bf16x8 vfA[4], vfB[4];
    load_V(vfA, Vw, 0);

    #pragma unroll 1
    for (int it2 = 0; it2 < L_ / MT / 2; ++it2) {
        const int m0 = it2 * (2 * MT);
        ATTN_ITER(KsB0, KsB1, vfA, vfB, m0, false)
        ATTN_ITER(KsB1, KsB0, vfB, vfA, m0 + MT, true)
    }

    // ---- denom: reduce over 16 n-lanes, combine mt halves via LDS
    #pragma unroll
    for (int d = 1; d < 16; d <<= 1) {
        #pragma unroll
        for (int lt = 0; lt < 2; ++lt)
            #pragma unroll
            for (int r = 0; r < 4; ++r)
                dn[lt][r] += __shfl_xor(dn[lt][r], d, 64);
    }
    __syncthreads();   // all waves past last O-phase (P/K reads done) before Dsh writes
    if (n == 0) {
        #pragma unroll
        for (int lt = 0; lt < 2; ++lt)
            #pragma unroll
            for (int r = 0; r < 4; ++r)
                Dsh[mt * 64 + 32 * g + 16 * lt + 4 * q + r] = dn[lt][r];
    }
    __syncthreads();

    float rden[4][4];
    #pragma unroll
    for (int lt = 0; lt < 4; ++lt)
        #pragma unroll
        for (int r = 0; r < 4; ++r) {
            int l = 16 * lt + 4 * q + r;
            rden[lt][r] = 1.0f / (Dsh[l] + Dsh[64 + l]);
        }

    // ---- direct stores: lane's f32x4 is 4 contiguous l -> fully-coalesced 64-B/c-row sectors
    float* ob = out + (size_t)b * (C_ * L_) + l0;
    #pragma unroll
    for (int lt = 0; lt < 4; ++lt)
        #pragma unroll
        for (int ct = 0; ct < 4; ++ct) {
            int c = 64 * w + 16 * ct + n;
            float4 val;
            val.x = Oacc[lt][ct][0] * rden[lt][0];
            val.y = Oacc[lt][ct][1] * rden[lt][1];
            val.z = Oacc[lt][ct][2] * rden[lt][2];
            val.w = Oacc[lt][ct][3] * rden[lt][3];
            *(float4*)(ob + (size_t)c * L_ + 16 * lt + 4 * q) = val;
        }
}

extern "C" void kernel_launch(void* const* d_in, const int* in_sizes, int n_in,
                              void* d_out, int out_size, void* d_ws, size_t ws_size,
                              hipStream_t stream) {
    const float* Q    = (const float*)d_in[0];
    const float* K    = (const float*)d_in[1];
    const float* V    = (const float*)d_in[2];
    const float* mask = (const float*)d_in[3];
    float* out = (float*)d_out;

    // workspace: Kt | Vb, each B*L*C bf16 = 16 MiB
    short* Kt = (short*)d_ws;
    short* Vb = Kt + (size_t)B_ * L_ * C_;

    prepass_kernel<<<4608, 256, 0, stream>>>(K, V, mask, Kt, Vb);
    attn_main<<<512, 256, 0, stream>>>(Q, Kt, Vb, mask, out);
}

// Round 6
// 230.732 us; speedup vs baseline: 1.0287x; 1.0287x over previous
//
#include <hip/hip_runtime.h>
#include <hip/hip_bf16.h>

#define B_ 16
#define C_ 256
#define L_ 2048
#define MT 32   // m-tile per iteration

typedef __attribute__((ext_vector_type(8))) short bf16x8;
typedef __attribute__((ext_vector_type(4))) float f32x4;

#define CEXP 0.09016844005556021f   // (1/16) * log2(e), folded into Q conversion

// round-to-nearest-even float -> bf16
__device__ __forceinline__ short f2bf_rne(float f) {
    union { float f; unsigned u; } x; x.f = f;
    unsigned r = x.u + 0x7fffu + ((x.u >> 16) & 1u);
    return (short)(r >> 16);
}

// direct global->LDS DMA, 16 bytes per lane; LDS dest = wave-uniform base + lane*16
__device__ __forceinline__ void gld_lds16(const void* g, void* l) {
    __builtin_amdgcn_global_load_lds(
        (const __attribute__((address_space(1))) void*)g,
        (__attribute__((address_space(3))) void*)l, 16, 0, 0);
}

// ---------------- prepass: K transpose+cvt (blocks 0..511), V*mask cvt (512..4607) ----------
__global__ __launch_bounds__(256) void prepass_kernel(
        const float* __restrict__ Kin, const float* __restrict__ Vin,
        const float* __restrict__ mask,
        short* __restrict__ Kt, short* __restrict__ Vb) {
    const int bid = blockIdx.x;
    const int t = threadIdx.x;
    if (bid < 512) {
        __shared__ unsigned short tile[64 * 256];   // 32 KB, phys chunk = (c>>3) ^ (l&31)
        const int b  = bid >> 5;
        const int l0 = (bid & 31) * 64;
        #pragma unroll
        for (int iter = 0; iter < 16; ++iter) {
            int idx = iter * 256 + t;              // 0..4095
            int ci = idx >> 4;                     // 0..255
            int lc = (idx & 15) * 4;               // l-chunk of 4
            float4 v = *(const float4*)(Kin + ((size_t)(b * C_ + ci)) * L_ + l0 + lc);
            float vv[4] = {v.x, v.y, v.z, v.w};
            #pragma unroll
            for (int j = 0; j < 4; ++j) {
                int l = lc + j;
                tile[l * 256 + (((ci >> 3) ^ (l & 31)) << 3) + (ci & 7)] =
                    (unsigned short)f2bf_rne(vv[j]);
            }
        }
        __syncthreads();
        #pragma unroll
        for (int iter = 0; iter < 8; ++iter) {
            int li = iter * 8 + (t >> 5);          // 0..63
            int ck = t & 31;                       // logical 16-B chunk
            uint4 val = *(const uint4*)(tile + li * 256 + ((ck ^ (li & 31)) << 3));
            *(uint4*)(Kt + ((size_t)(b * L_ + l0 + li)) * C_ + ck * 8) = val;
        }
    } else {
        // 4096 blocks x 256 threads x 8 elems = B_*C_*L_
        size_t e = ((size_t)(bid - 512) * 256 + t) * 8;
        int b = (int)(e >> 19);
        int m = (int)(e & (L_ - 1));
        const float4 v0 = *(const float4*)(Vin + e);
        const float4 v1 = *(const float4*)(Vin + e + 4);
        const float* mp = mask + ((size_t)b << 11) + m;
        const float4 m0 = *(const float4*)mp;
        const float4 m1 = *(const float4*)(mp + 4);
        uint4 o;
        o.x = (unsigned)(unsigned short)f2bf_rne(v0.x * m0.x)
            | ((unsigned)(unsigned short)f2bf_rne(v0.y * m0.y) << 16);
        o.y = (unsigned)(unsigned short)f2bf_rne(v0.z * m0.z)
            | ((unsigned)(unsigned short)f2bf_rne(v0.w * m0.w) << 16);
        o.z = (unsigned)(unsigned short)f2bf_rne(v1.x * m1.x)
            | ((unsigned)(unsigned short)f2bf_rne(v1.y * m1.y) << 16);
        o.w = (unsigned)(unsigned short)f2bf_rne(v1.z * m1.z)
            | ((unsigned)(unsigned short)f2bf_rne(v1.w * m1.w) << 16);
        *(uint4*)(Vb + e) = o;
    }
}

// ---- stage one 32-row K tile via DMA; XOR swizzle on the GLOBAL side ----
// K LDS: [m 0..31][slot p 0..31 of 16B]; phys slot p holds global chunk kc = p ^ m.
__device__ __forceinline__ void stage_K(const short* __restrict__ Ksrc,
                                        short* Ks, int m0, int t) {
    #pragma unroll
    for (int rr = 0; rr < 4; ++rr) {
        int G = rr * 256 + t;                  // 0..1023
        int m = G >> 5, p = G & 31;
        gld_lds16(Ksrc + ((size_t)(m0 + m) << 8) + ((p ^ m) << 3), Ks + G * 8);
    }
}

// V B-fragments direct global->register (B[k=8q+j][col=c] = Vb[c][m0+8q+j], 16B contiguous)
__device__ __forceinline__ void load_V(bf16x8 (&vf)[4], const short* __restrict__ Vw, int m0) {
    #pragma unroll
    for (int ct = 0; ct < 4; ++ct)
        vf[ct] = *(const bf16x8*)(Vw + (size_t)(ct * 16) * L_ + m0);
}

// O_{prev}: A-frags from P buffer (rho row permutation: l=16u+4a+b stored at 16u+4b+a),
// B-frags = V regs loaded >=1 iteration ago (drained at the barrier just crossed).
#define O_PHASE(PBUF, VF)                                                                  \
  {                                                                                        \
    bf16x8 af[4];                                                                          \
    _Pragma("unroll")                                                                      \
    for (int lt = 0; lt < 4; ++lt)                                                         \
      af[lt] = *(const bf16x8*)((PBUF) + (16 * lt + 4 * (n & 3) + (n >> 2)) * 40 + 8 * q); \
    _Pragma("unroll")                                                                      \
    for (int ct = 0; ct < 4; ++ct)                                                         \
      _Pragma("unroll")                                                                    \
      for (int lt = 0; lt < 4; ++lt)                                                       \
        Oacc[lt][ct] =                                                                     \
            __builtin_amdgcn_mfma_f32_16x16x32_bf16(af[lt], (VF)[ct], Oacc[lt][ct], 0, 0, 0); \
  }

// S_it: QK^T for this wave's 32 rows x 16 cols, exp2, denom, write P into PW0 base.
#define S_PHASE(KS, PW0)                                                                   \
  {                                                                                        \
    f32x4 S0 = fzero, S1 = fzero;                                                          \
    const short* Krow = (KS) + (16 * mt + n) * 256;                                        \
    _Pragma("unroll")                                                                      \
    for (int ks = 0; ks < 8; ++ks) {                                                       \
      bf16x8 bf = *(const bf16x8*)(Krow + (((4 * ks + q) ^ (16 * mt + n)) << 3));          \
      S0 = __builtin_amdgcn_mfma_f32_16x16x32_bf16(qf[0][ks], bf, S0, 0, 0, 0);            \
      S1 = __builtin_amdgcn_mfma_f32_16x16x32_bf16(qf[1][ks], bf, S1, 0, 0, 0);            \
    }                                                                                      \
    _Pragma("unroll")                                                                      \
    for (int r = 0; r < 4; ++r) {                                                          \
      float p0 = wv * exp2f(S0[r]);                                                        \
      dn[0][r] += p0;                                                                      \
      (PW0)[(4 * r) * 40] = f2bf_rne(p0);                                                  \
      float p1 = wv * exp2f(S1[r]);                                                        \
      dn[1][r] += p1;                                                                      \
      (PW0)[(16 + 4 * r) * 40] = f2bf_rne(p1);                                             \
    }                                                                                      \
  }

// ---------------- main fused attention (single barrier / iter, lag-1 O-phase) ------------
// 512 blocks (b = bid&15 -> same-batch blocks share an XCD; l0 = (bid>>4)*64), 4 waves.
// S-phase: wave (g=w&1, mt=w>>1): rows 32g..32g+31 x col m=16mt+n.
// O-phase (lagged 1 iter): wave w: cols [64w,64w+64) x 64 l.
__global__ __launch_bounds__(256, 2) void attn_main(
        const float* __restrict__ Qin,  // [B][C][L] fp32
        const short* __restrict__ Kt,   // [B][L][C] bf16
        const short* __restrict__ Vb,   // [B][C][L] bf16, mask-scaled
        const float* __restrict__ mask, // [B][L]
        float* __restrict__ out) {      // [B][C][L]
    __shared__ __align__(16) char smem[43520];
    short* KsB0 = (short*)smem;                 // 16 KB  (even m-tiles)
    short* KsB1 = (short*)(smem + 16384);       // 16 KB  (odd m-tiles)
    short* PA   = (short*)(smem + 32768);       // [64 rho][40 sh] = 5120 B (even P)
    short* PB   = (short*)(smem + 37888);       // 5120 B (odd P)
    float* Dsh  = (float*)(smem + 43008);       // [2][64] partial denoms

    const int t = threadIdx.x;
    const int w = t >> 6, lane = t & 63, q = lane >> 4, n = lane & 15;
    const int g = w & 1, mt = w >> 1;

    const int b  = blockIdx.x & 15;
    const int l0 = (blockIdx.x >> 4) * 64;

    const short* Ksrc = Kt + (size_t)b * (L_ * C_);
    const short* Vsrc = Vb + (size_t)b * (C_ * L_);
    const float* mrow = mask + (size_t)b * L_;
    const short* Vw   = Vsrc + (size_t)(64 * w + n) * L_ + 8 * q;
    short* Pw0A = PA + (32 * g + q) * 40 + 16 * mt + n;
    short* Pw0B = PB + (32 * g + q) * 40 + 16 * mt + n;

    // ---- Q A-frags straight from global fp32 (one-time; blocks partition l)
    bf16x8 qf[2][8];
    {
        const float* Qb = Qin + (size_t)b * (C_ * L_) + (l0 + 32 * g + n);
        #pragma unroll
        for (int lt = 0; lt < 2; ++lt)
            #pragma unroll
            for (int ks = 0; ks < 8; ++ks) {
                bf16x8 v;
                #pragma unroll
                for (int j = 0; j < 8; ++j) {
                    float f = Qb[(size_t)(32 * ks + 8 * q + j) * L_ + 16 * lt];
                    v[j] = f2bf_rne(f * CEXP);
                }
                qf[lt][ks] = v;
            }
    }

    const f32x4 fzero = {0.f, 0.f, 0.f, 0.f};
    f32x4 Oacc[4][4];
    #pragma unroll
    for (int i = 0; i < 4; ++i)
        #pragma unroll
        for (int j = 0; j < 4; ++j) Oacc[i][j] = fzero;
    float dn[2][4] = {{0.f,0.f,0.f,0.f},{0.f,0.f,0.f,0.f}};

    // prologue: tile 0 -> K buf 0, V reg set A; mask for tile 0
    stage_K(Ksrc, KsB0, 0, t);
    bf16x8 vfA[4], vfB[4];
    load_V(vfA, Vw, 0);
    float wv = mrow[16 * mt + n] + 1e-9f;

    #pragma unroll 1
    for (int it2 = 0; it2 < L_ / MT / 2; ++it2) {
        const int m0a = it2 * (2 * MT);         // even iter
        const int m0b = m0a + MT;               // odd iter

        // ======== even iteration (c=0): K in KsB0, P->PA; O_{prev} from PB/vfB ========
        __syncthreads();   // K[m0a] landed; P/V of prev iter drained; PB free after O
        if (m0a != 0) O_PHASE(PB, vfB)
        // prefetch tile m0a+MT (always exists): K->KsB1, V->vfB (freed by O above)
        stage_K(Ksrc, KsB1, m0a + MT, t);
        load_V(vfB, Vw, m0a + MT);
        float wvn0 = mrow[m0a + MT + 16 * mt + n] + 1e-9f;
        S_PHASE(KsB0, Pw0A)
        wv = wvn0;

        // ======== odd iteration (c=1): K in KsB1, P->PB; O_{prev} from PA/vfA ========
        __syncthreads();
        O_PHASE(PA, vfA)
        float wvn1 = 0.f;
        if (m0b + MT < L_) {
            stage_K(Ksrc, KsB0, m0b + MT, t);
            load_V(vfA, Vw, m0b + MT);
            wvn1 = mrow[m0b + MT + 16 * mt + n] + 1e-9f;
        }
        S_PHASE(KsB1, Pw0B)
        wv = wvn1;
    }

    // final lagged O-phase for the last (odd) tile
    __syncthreads();
    O_PHASE(PB, vfB)

    // ---- denom: reduce over 16 n-lanes, combine mt halves via LDS
    #pragma unroll
    for (int d = 1; d < 16; d <<= 1) {
        #pragma unroll
        for (int lt = 0; lt < 2; ++lt)
            #pragma unroll
            for (int r = 0; r < 4; ++r)
                dn[lt][r] += __shfl_xor(dn[lt][r], d, 64);
    }
    if (n == 0) {
        #pragma unroll
        for (int lt = 0; lt < 2; ++lt)
            #pragma unroll
            for (int r = 0; r < 4; ++r)
                Dsh[mt * 64 + 32 * g + 16 * lt + 4 * q + r] = dn[lt][r];
    }
    __syncthreads();

    float rden[4][4];
    #pragma unroll
    for (int lt = 0; lt < 4; ++lt)
        #pragma unroll
        for (int r = 0; r < 4; ++r) {
            int l = 16 * lt + 4 * q + r;
            rden[lt][r] = 1.0f / (Dsh[l] + Dsh[64 + l]);
        }

    // ---- direct stores: lane's f32x4 = 4 contiguous l -> coalesced 64-B sectors per c-row
    float* ob = out + (size_t)b * (C_ * L_) + l0;
    #pragma unroll
    for (int lt = 0; lt < 4; ++lt)
        #pragma unroll
        for (int ct = 0; ct < 4; ++ct) {
            int c = 64 * w + 16 * ct + n;
            float4 val;
            val.x = Oacc[lt][ct][0] * rden[lt][0];
            val.y = Oacc[lt][ct][1] * rden[lt][1];
            val.z = Oacc[lt][ct][2] * rden[lt][2];
            val.w = Oacc[lt][ct][3] * rden[lt][3];
            *(float4*)(ob + (size_t)c * L_ + 16 * lt + 4 * q) = val;
        }
}

extern "C" void kernel_launch(void* const* d_in, const int* in_sizes, int n_in,
                              void* d_out, int out_size, void* d_ws, size_t ws_size,
                              hipStream_t stream) {
    const float* Q    = (const float*)d_in[0];
    const float* K    = (const float*)d_in[1];
    const float* V    = (const float*)d_in[2];
    const float* mask = (const float*)d_in[3];
    float* out = (float*)d_out;

    // workspace: Kt | Vb, each B*L*C bf16 = 16 MiB
    short* Kt = (short*)d_ws;
    short* Vb = Kt + (size_t)B_ * L_ * C_;

    prepass_kernel<<<4608, 256, 0, stream>>>(K, V, mask, Kt, Vb);
    attn_main<<<512, 256, 0, stream>>>(Q, Kt, Vb, mask, out);
}